// Round 5
// baseline (316.359 us; speedup 1.0000x reference)
//
#include <hip/hip_runtime.h>
#include <hip/hip_bf16.h>

// B=64, L=256, D=1024, F=1024 (fp32).
//   A = X @ W0, C = X @ W1  (X as [16384, 1024])
//   per (b,f): h1 = max-prefix of a; h2 = max_t(h1_{t-1}+c_t); out = tanh(h2+bias)
//
// R18 = R17 (fused prep + software grid barrier + dual fp4 MX GEMM/scan,
// 512 blocks x 256 thr, 2 blocks/CU co-resident: LDS 56.4 KB) + SPILL FIX:
// R17's rocprof showed VGPR_Count=128 with ~110 MB excess FETCH and ~119 MB
// excess WRITE (scratch round-trips) and MfmaUtil 2.9% -- the allocator
// targeted a 128-reg budget (launch_bounds 2nd arg is only a MINIMUM
// waves/EU, i.e. a VGPR cap, not a floor) and spilled the 128-float
// accumulators. amdgpu_waves_per_eu(2,2) pins the occupancy target so the
// allocator gets the full 256-reg budget (LDS already caps at 2 blocks/CU,
// so max=2 costs nothing). Phase-1 X-loop unroll capped at 2 to cut peak
// pressure. All compute logic byte-identical to R17 (which passed).

#define GLOBAL_AS __attribute__((address_space(1)))
#define LDS_AS __attribute__((address_space(3)))

typedef int v8i __attribute__((ext_vector_type(8)));
typedef float floatx16 __attribute__((ext_vector_type(16)));

__device__ __forceinline__ void async_copy16(const void* g, void* l) {
    __builtin_amdgcn_global_load_lds((GLOBAL_AS void*)g, (LDS_AS void*)l, 16, 0, 0);
}

struct Seg { float A, C, AC; };

__device__ __forceinline__ Seg segCombine(const Seg& x, const Seg& y) {   // x precedes y in l
    Seg r;
    r.AC = fmaxf(fmaxf(x.AC, y.AC), x.A + y.C);
    r.A  = fmaxf(x.A, y.A);
    r.C  = fmaxf(x.C, y.C);
    return r;
}

__device__ __forceinline__ Seg segShflXor(const Seg& s, int m) {
    Seg r;
    r.A  = __shfl_xor(s.A,  m, 64);
    r.C  = __shfl_xor(s.C,  m, 64);
    r.AC = __shfl_xor(s.AC, m, 64);
    return r;
}

// ---- fp4 e2m1 encode (RNE thresholds; mags {0,.5,1,1.5,2,3,4,6}) ---------
__device__ __forceinline__ unsigned f2fp4(float x) {
    unsigned s = (__float_as_uint(x) >> 28) & 8u;
    float a = fabsf(x);
    unsigned m = (a < 0.25f) ? 0u :
                 (a < 0.75f) ? 1u :
                 (a < 1.25f) ? 2u :
                 (a < 1.75f) ? 3u :
                 (a < 2.5f)  ? 4u :
                 (a < 3.5f)  ? 5u :
                 (a < 5.0f)  ? 6u : 7u;
    return s | m;
}

__device__ __forceinline__ unsigned pack8fp4(float4 a, float4 b, float s) {
    return  f2fp4(s * a.x)        | (f2fp4(s * a.y) << 4)  |
           (f2fp4(s * a.z) << 8)  | (f2fp4(s * a.w) << 12) |
           (f2fp4(s * b.x) << 16) | (f2fp4(s * b.y) << 20) |
           (f2fp4(s * b.z) << 24) | (f2fp4(s * b.w) << 28);
}

// ---- software grid barrier (single-use per launch; cnt pre-zeroed) -------
__device__ __forceinline__ void gridBarrier(unsigned* cnt, unsigned expected) {
    __syncthreads();                 // all threads in block done with phase 1
    __threadfence();                 // device-scope release (L2 writeback)
    if (threadIdx.x == 0) {
        __hip_atomic_fetch_add(cnt, 1u, __ATOMIC_RELEASE, __HIP_MEMORY_SCOPE_AGENT);
        while (__hip_atomic_load(cnt, __ATOMIC_ACQUIRE, __HIP_MEMORY_SCOPE_AGENT)
               < expected)
            __builtin_amdgcn_s_sleep(2);
    }
    __syncthreads();                 // release the rest of the block
    __threadfence();                 // device-scope acquire (invalidate stale lines)
}

// ---- fused: prep (phase 1) + grid barrier + dual fp4-GEMM/scan (phase 2) -
__global__ __launch_bounds__(256)
__attribute__((amdgpu_waves_per_eu(2, 2)))
void fused(const float* __restrict__ X,
           const float* __restrict__ W0,
           const float* __restrict__ W1,
           const float* __restrict__ bias,
           float* __restrict__ out,
           unsigned char* __restrict__ Xf4,
           unsigned char* __restrict__ W0t,
           unsigned char* __restrict__ W1t,
           unsigned* __restrict__ barrier_cnt) {
    __shared__ unsigned char As[256 * 128];   // 32 KB: 256 rows x 128 k-bytes
    __shared__ unsigned char Bs0[64 * 128];   //  8 KB
    __shared__ unsigned char Bs1[64 * 128];   //  8 KB
    __shared__ float sumBuf[64][4][3];        //  3 KB
    __shared__ float tilef[32][33];           //  4.2 KB   (total 56.4 KB -> 2 blk/CU)

    int bid = blockIdx.x;                     // 0..511
    int t = threadIdx.x;
    int lane = t & 63, wave = t >> 6;

    // ================= phase 1: prep (distributed) ========================
    // X fp32 -> fp4 (x2): 4096 units of 256x16 floats; 8 units/block.
    #pragma unroll 2
    for (int uu = 0; uu < 8; uu++) {
        size_t i = ((size_t)(bid * 8 + uu)) * 256 + t;
        const float4* src = (const float4*)X + i * 4;
        float4 v0 = src[0], v1 = src[1], v2 = src[2], v3 = src[3];
        uint2 o;
        o.x = pack8fp4(v0, v1, 2.0f);
        o.y = pack8fp4(v2, v3, 2.0f);
        ((uint2*)Xf4)[i] = o;
    }
    // W transpose + fp4 (x128): 2048 32x32 tile-units; 4 units/block.
    for (int uu = 0; uu < 4; uu++) {
        int bw = bid * 4 + uu;                // 0..2047
        const float* W = (bw >= 1024) ? W1 : W0;
        unsigned char* Wt = (bw >= 1024) ? W1t : W0t;
        int tile = bw & 1023;
        int n0t = (tile & 31) * 32, k0t = (tile >> 5) * 32;
        int tx = t & 31, ty = t >> 5;         // 32x8
        __syncthreads();                      // tilef reuse across units
        #pragma unroll
        for (int j = 0; j < 32; j += 8)
            tilef[tx][ty + j] = W[(size_t)(k0t + ty + j) * 1024 + n0t + tx];  // [n][k]
        __syncthreads();
        if (t < 128) {
            int n = t >> 2, kq = (t & 3) * 8; // 8 k-elems -> 4 bytes
            float4 a = make_float4(tilef[n][kq],     tilef[n][kq + 1],
                                   tilef[n][kq + 2], tilef[n][kq + 3]);
            float4 b = make_float4(tilef[n][kq + 4], tilef[n][kq + 5],
                                   tilef[n][kq + 6], tilef[n][kq + 7]);
            unsigned p = pack8fp4(a, b, 128.0f);
            ((unsigned*)Wt)[(((size_t)(n0t + n) * 512 + (k0t >> 1)) >> 2) + (t & 3)] = p;
        }
    }

    gridBarrier(barrier_cnt, 512);

    // ================= phase 2: two gemm+scan jobs ========================
    int m31 = lane & 31;             // A m-row / B n-row / C col
    int kh  = lane >> 5;             // k-half: 16B fp4 block = 32 k
    int wm  = wave * 64;
    int srow = t >> 3;               // 0..31 (staging row within panel)
    int schunk = (t & 7) ^ (srow & 7);

    for (int pass = 0; pass < 2; pass++) {
        int job = bid * 2 + pass;    // 0..1023
        int bX = job >> 4;           // batch 0..63
        int n0 = (job & 15) * 64;    // f-tile
        size_t m0 = (size_t)bX * 256;

        const unsigned char* gA  = Xf4 + (m0 + (size_t)srow) * 512 + schunk * 16;
        const unsigned char* gB0 = W0t + ((size_t)(n0 + srow)) * 512 + schunk * 16;
        const unsigned char* gB1 = W1t + ((size_t)(n0 + srow)) * 512 + schunk * 16;

        floatx16 acc0[2][2] = {};    // X@W0 -> a (scaled x256)  [mb][j]
        floatx16 acc1[2][2] = {};    // X@W1 -> c (scaled x256)

        for (int k0 = 0; k0 < 1024; k0 += 256) {
            int kb = k0 >> 1;        // byte offset within a 512 B row
            __syncthreads();
            #pragma unroll
            for (int p = 0; p < 8; p++)   // A: 8 x 32-row panels
                async_copy16(gA + kb + (size_t)(p * 32) * 512, &As[p * 4096 + t * 16]);
            #pragma unroll
            for (int p = 0; p < 2; p++) { // B: 2 x 32-row panels each
                async_copy16(gB0 + kb + (size_t)(p * 32) * 512, &Bs0[p * 4096 + t * 16]);
                async_copy16(gB1 + kb + (size_t)(p * 32) * 512, &Bs1[p * 4096 + t * 16]);
            }
            __syncthreads();

            #pragma unroll
            for (int kk = 0; kk < 4; kk++) {
                int soff = ((kk * 2 + kh) ^ (m31 & 7)) * 16;   // swizzled slot
                v8i af[2];
                #pragma unroll
                for (int mb = 0; mb < 2; mb++) {
                    uint4 x = *(const uint4*)&As[(wm + mb * 32 + m31) * 128 + soff];
                    af[mb][0] = x.x; af[mb][1] = x.y; af[mb][2] = x.z; af[mb][3] = x.w;
                    af[mb][4] = 0; af[mb][5] = 0; af[mb][6] = 0; af[mb][7] = 0;
                }
                #pragma unroll
                for (int j = 0; j < 2; j++) {
                    uint4 x0 = *(const uint4*)&Bs0[(j * 32 + m31) * 128 + soff];
                    uint4 x1 = *(const uint4*)&Bs1[(j * 32 + m31) * 128 + soff];
                    v8i b0, b1;
                    b0[0] = x0.x; b0[1] = x0.y; b0[2] = x0.z; b0[3] = x0.w;
                    b0[4] = 0; b0[5] = 0; b0[6] = 0; b0[7] = 0;
                    b1[0] = x1.x; b1[1] = x1.y; b1[2] = x1.z; b1[3] = x1.w;
                    b1[4] = 0; b1[5] = 0; b1[6] = 0; b1[7] = 0;
                    #pragma unroll
                    for (int mb = 0; mb < 2; mb++) {
                        acc0[mb][j] = __builtin_amdgcn_mfma_scale_f32_32x32x64_f8f6f4(
                            af[mb], b0, acc0[mb][j], 4, 4, 0, 0x7f7f7f7f, 0, 0x7f7f7f7f);
                        acc1[mb][j] = __builtin_amdgcn_mfma_scale_f32_32x32x64_f8f6f4(
                            af[mb], b1, acc1[mb][j], 4, 4, 0, 0x7f7f7f7f, 0, 0x7f7f7f7f);
                    }
                }
            }
        }

        // ---- in-register scan reduction ----------------------------------
        // C/D 32x32: col = lane&31, row = (reg&3) + 8*(reg>>2) + 4*kh.
        const float NEG = -1e30f;
        #pragma unroll
        for (int j = 0; j < 2; j++) {
            Seg Smb[2];
            #pragma unroll
            for (int mb = 0; mb < 2; mb++) {
                Seg Kk[4];
                #pragma unroll
                for (int k = 0; k < 4; k++) {
                    float run = NEG, Cm = NEG, ACm = NEG;
                    #pragma unroll
                    for (int r = 0; r < 4; r++) {
                        float c = acc1[mb][j][k * 4 + r];
                        ACm = fmaxf(ACm, run + c);
                        Cm  = fmaxf(Cm, c);
                        run = fmaxf(run, acc0[mb][j][k * 4 + r]);
                    }
                    Kk[k].A = run; Kk[k].C = Cm; Kk[k].AC = ACm;
                }
                #pragma unroll
                for (int k = 0; k < 4; k++) {
                    Seg o = segShflXor(Kk[k], 32);
                    Seg lo = kh ? o : Kk[k];          // rows 8k..8k+3
                    Seg hi = kh ? Kk[k] : o;          // rows 8k+4..8k+7
                    Kk[k] = segCombine(lo, hi);
                }
                Smb[mb] = segCombine(segCombine(Kk[0], Kk[1]),
                                     segCombine(Kk[2], Kk[3]));
            }
            Seg Wv = segCombine(Smb[0], Smb[1]);      // rows wm..wm+63 in l-order
            if (lane < 32) {
                int col = j * 32 + m31;
                sumBuf[col][wave][0] = Wv.A;   // wave index == l-order of 64-row group
                sumBuf[col][wave][1] = Wv.C;
                sumBuf[col][wave][2] = Wv.AC;
            }
        }
        __syncthreads();
        if (t < 64) {
            Seg w;
            w.A = sumBuf[t][0][0]; w.C = sumBuf[t][0][1]; w.AC = sumBuf[t][0][2];
            #pragma unroll
            for (int g = 1; g < 4; g++) {
                Seg y;
                y.A = sumBuf[t][g][0]; y.C = sumBuf[t][g][1]; y.AC = sumBuf[t][g][2];
                w = segCombine(w, y);
            }
            // un-scale: a,c carried x256 (X x2, W x128); max-plus commutes with it
            float h2 = fmaxf(0.f, fmaxf(w.C, w.AC)) * (1.0f / 256.0f);
            out[(size_t)bX * 1024 + n0 + t] = tanhf(h2 + bias[n0 + t]);
        }
    }
}

extern "C" void kernel_launch(void* const* d_in, const int* in_sizes, int n_in,
                              void* d_out, int out_size, void* d_ws, size_t ws_size,
                              hipStream_t stream) {
    const float* X    = (const float*)d_in[0];  // [64,256,1024]
    const float* W0   = (const float*)d_in[1];  // [1024,1024]
    const float* W1   = (const float*)d_in[2];  // [1024,1024]
    const float* bias = (const float*)d_in[3];  // [1024]
    float* out = (float*)d_out;                 // [64,1024]

    char* ws = (char*)d_ws;
    unsigned char* Xf4 = (unsigned char*)(ws);              // 8 MB
    unsigned char* W0t = (unsigned char*)(ws + 8388608);    // 512 KB
    unsigned char* W1t = (unsigned char*)(ws + 8912896);    // 512 KB
    unsigned* barrier_cnt = (unsigned*)(ws + 9437184);      // 128 B

    // workspace is re-poisoned each iteration: zero the barrier counter
    // on-stream (memset nodes are graph-capturable).
    hipMemsetAsync(barrier_cnt, 0, 128, stream);

    fused<<<dim3(512), dim3(256), 0, stream>>>(X, W0, W1, bias, out,
                                               Xf4, W0t, W1t, barrier_cnt);
}

// Round 6
// 120.095 us; speedup vs baseline: 2.6342x; 2.6342x over previous
//
#include <hip/hip_runtime.h>
#include <hip/hip_bf16.h>

// B=64, L=256, D=1024, F=1024 (fp32).
//   A = X @ W0, C = X @ W1  (X as [16384, 1024])
//   per (b,f): h1 = max-prefix of a; h2 = max_t(h1_{t-1}+c_t); out = tanh(h2+bias)
//
// R19 = exact revert to R13 (best measured: 122.97 us).
// Post-mortem trail since: R14 2-phase dbuf = null (+3 us); R15 32x32x64
// MFMA = null (+2 us); R16 cooperative fusion = launch illegal under graph
// capture; R17/R18 software-barrier fusion = 2.5x regression (233 us fused:
// VGPR_Count pinned at 128 with ~226 MB excess L2-fabric traffic, immune to
// waves_per_eu/launch_bounds hints). Conclusions: harness poison fills are
// ~82 us/iter (immovable); prep+gemm ~= 41 us combined; gemm_scan sits at a
// balanced LDS/MFMA operating point insensitive to schedule and MFMA-shape
// changes; job->XCD mapping already gives per-batch A-panel L2 locality.
//
// Kernel: fp4-e2m1 MX GEMM (16x16x128, unit scales, X x2 / W x128 with /256
// epilogue), block = one batch element x 64 f-cols, in-block max-plus scan +
// tanh. BK=256: fp4 rows are 512 B so a 128 B/row stage fits 52 KB LDS
// (As 32 KB, Bs 8+8 KB) with 4 barrier pairs. 3-bit XOR chunk swizzle
// (slot = chunk ^ (row&7)); wave bank load at the b128 floor.

#define GLOBAL_AS __attribute__((address_space(1)))
#define LDS_AS __attribute__((address_space(3)))

typedef int v8i __attribute__((ext_vector_type(8)));
typedef float floatx4 __attribute__((ext_vector_type(4)));

__device__ __forceinline__ void async_copy16(const void* g, void* l) {
    __builtin_amdgcn_global_load_lds((GLOBAL_AS void*)g, (LDS_AS void*)l, 16, 0, 0);
}

struct Seg { float A, C, AC; };

__device__ __forceinline__ Seg segCombine(const Seg& x, const Seg& y) {   // x precedes y in l
    Seg r;
    r.AC = fmaxf(fmaxf(x.AC, y.AC), x.A + y.C);
    r.A  = fmaxf(x.A, y.A);
    r.C  = fmaxf(x.C, y.C);
    return r;
}

__device__ __forceinline__ Seg segShflDown(const Seg& s, int d) {
    Seg r;
    r.A  = __shfl_down(s.A,  d, 64);
    r.C  = __shfl_down(s.C,  d, 64);
    r.AC = __shfl_down(s.AC, d, 64);
    return r;
}

// ---- fp4 e2m1 encode (RNE thresholds; mags {0,.5,1,1.5,2,3,4,6}) ---------
__device__ __forceinline__ unsigned f2fp4(float x) {
    unsigned s = (__float_as_uint(x) >> 28) & 8u;
    float a = fabsf(x);
    unsigned m = (a < 0.25f) ? 0u :
                 (a < 0.75f) ? 1u :
                 (a < 1.25f) ? 2u :
                 (a < 1.75f) ? 3u :
                 (a < 2.5f)  ? 4u :
                 (a < 3.5f)  ? 5u :
                 (a < 5.0f)  ? 6u : 7u;
    return s | m;
}

__device__ __forceinline__ unsigned pack8fp4(float4 a, float4 b, float s) {
    return  f2fp4(s * a.x)        | (f2fp4(s * a.y) << 4)  |
           (f2fp4(s * a.z) << 8)  | (f2fp4(s * a.w) << 12) |
           (f2fp4(s * b.x) << 16) | (f2fp4(s * b.y) << 20) |
           (f2fp4(s * b.z) << 24) | (f2fp4(s * b.w) << 28);
}

// ---- prep: X fp32->fp4 x2 (blocks 0..4095) + W x128 transpose (4096..6143)
__global__ __launch_bounds__(256) void prep(const float* __restrict__ X,
                                            const float* __restrict__ W0,
                                            const float* __restrict__ W1,
                                            unsigned char* __restrict__ Xf4,
                                            unsigned char* __restrict__ W0t,
                                            unsigned char* __restrict__ W1t) {
    __shared__ float tilef[32][33];
    int bx = blockIdx.x, t = threadIdx.x;
    if (bx < 4096) {
        // 16 consecutive floats -> 8 bytes (uint2), stores coalesced
        size_t i = (size_t)bx * 256 + t;
        const float4* src = (const float4*)X + i * 4;
        float4 v0 = src[0], v1 = src[1], v2 = src[2], v3 = src[3];
        uint2 o;
        o.x = pack8fp4(v0, v1, 2.0f);
        o.y = pack8fp4(v2, v3, 2.0f);
        ((uint2*)Xf4)[i] = o;
    } else {
        int bw = bx - 4096;                       // 0..2047
        const float* W = (bw >= 1024) ? W1 : W0;
        unsigned char* Wt = (bw >= 1024) ? W1t : W0t;
        int tile = bw & 1023;
        int n0t = (tile & 31) * 32, k0t = (tile >> 5) * 32;
        int tx = t & 31, ty = t >> 5;             // 32x8
        #pragma unroll
        for (int j = 0; j < 32; j += 8)
            tilef[tx][ty + j] = W[(size_t)(k0t + ty + j) * 1024 + n0t + tx];  // [n][k]
        __syncthreads();
        if (t < 128) {
            int n = t >> 2, kq = (t & 3) * 8;     // 8 k-elems -> 4 bytes
            float4 a = make_float4(tilef[n][kq],     tilef[n][kq + 1],
                                   tilef[n][kq + 2], tilef[n][kq + 3]);
            float4 b = make_float4(tilef[n][kq + 4], tilef[n][kq + 5],
                                   tilef[n][kq + 6], tilef[n][kq + 7]);
            unsigned p = pack8fp4(a, b, 128.0f);
            ((unsigned*)Wt)[(((size_t)(n0t + n) * 512 + (k0t >> 1)) >> 2) + (t & 3)] = p;
        }
    }
}

// ---- Fused dual fp4-GEMM (16x16x128 MX, unit scales) + scan + tanh -------
// grid (64 b, 16 n-tiles), 256 threads (4 waves). Block tile 256x64 dual.
// fp4 rows = 512 B; BK=256 -> 128 B/row stage, 4 barrier pairs total.
__global__ __launch_bounds__(256, 2) void gemm_scan(const unsigned char* __restrict__ Xf4,
                                                    const unsigned char* __restrict__ W0t,
                                                    const unsigned char* __restrict__ W1t,
                                                    const float* __restrict__ bias,
                                                    float* __restrict__ out) {
    __shared__ unsigned char As[256 * 128];   // 32 KB: 256 rows x 128 k-bytes
    __shared__ unsigned char Bs0[64 * 128];   //  8 KB
    __shared__ unsigned char Bs1[64 * 128];
    __shared__ float sumBuf[64][4][3];

    int t = threadIdx.x;
    int lane = t & 63, wave = t >> 6;
    int n0 = blockIdx.y * 64;
    size_t m0 = (size_t)blockIdx.x * 256;

    // staging (BK=256 -> 128 B/row): 8 chunks/row. Thread t -> row t>>3, dest
    // slot t&7; SOURCE chunk (t&7)^(row&7) (row&7 invariant under +32-row
    // panel steps). LDS dest stays t*16 (m104-legal).
    int srow = t >> 3;
    int schunk = (t & 7) ^ (srow & 7);
    const unsigned char* gA  = Xf4 + (m0 + (size_t)srow) * 512 + schunk * 16;
    const unsigned char* gB0 = W0t + ((size_t)(n0 + srow)) * 512 + schunk * 16;
    const unsigned char* gB1 = W1t + ((size_t)(n0 + srow)) * 512 + schunk * 16;

    floatx4 acc0[4][4] = {};   // X@W0 -> a (scaled x256)
    floatx4 acc1[4][4] = {};   // X@W1 -> c (scaled x256)
    int wm = wave * 64;
    int mrow = lane & 15;            // A m-row / B n-row / C col
    int q = lane >> 4;               // k-quarter (16-byte fp4 block = 32 k)

    for (int k0 = 0; k0 < 1024; k0 += 256) {
        int kb = k0 >> 1;            // byte offset within a row
        __syncthreads();
        #pragma unroll
        for (int p = 0; p < 8; p++)  // A: 8 x 32-row panels
            async_copy16(gA + kb + (size_t)(p * 32) * 512, &As[p * 4096 + t * 16]);
        #pragma unroll
        for (int p = 0; p < 2; p++) { // B: 2 x 32-row panels each
            async_copy16(gB0 + kb + (size_t)(p * 32) * 512, &Bs0[p * 4096 + t * 16]);
            async_copy16(gB1 + kb + (size_t)(p * 32) * 512, &Bs1[p * 4096 + t * 16]);
        }
        __syncthreads();

        #pragma unroll
        for (int kk = 0; kk < 2; kk++) {
            int soff = ((kk * 4 + q) ^ (mrow & 7)) * 16;   // swizzled slot
            v8i af[4];
            #pragma unroll
            for (int i = 0; i < 4; i++) {
                uint4 x = *(const uint4*)&As[(wm + i * 16 + mrow) * 128 + soff];
                af[i][0] = x.x; af[i][1] = x.y; af[i][2] = x.z; af[i][3] = x.w;
                af[i][4] = 0; af[i][5] = 0; af[i][6] = 0; af[i][7] = 0;
            }
            #pragma unroll
            for (int j = 0; j < 4; j++) {
                uint4 x0 = *(const uint4*)&Bs0[(j * 16 + mrow) * 128 + soff];
                uint4 x1 = *(const uint4*)&Bs1[(j * 16 + mrow) * 128 + soff];
                v8i b0, b1;
                b0[0] = x0.x; b0[1] = x0.y; b0[2] = x0.z; b0[3] = x0.w;
                b0[4] = 0; b0[5] = 0; b0[6] = 0; b0[7] = 0;
                b1[0] = x1.x; b1[1] = x1.y; b1[2] = x1.z; b1[3] = x1.w;
                b1[4] = 0; b1[5] = 0; b1[6] = 0; b1[7] = 0;
                #pragma unroll
                for (int i = 0; i < 4; i++) {
                    acc0[i][j] = __builtin_amdgcn_mfma_scale_f32_16x16x128_f8f6f4(
                        af[i], b0, acc0[i][j], 4, 4, 0, 0x7f7f7f7f, 0, 0x7f7f7f7f);
                    acc1[i][j] = __builtin_amdgcn_mfma_scale_f32_16x16x128_f8f6f4(
                        af[i], b1, acc1[i][j], 4, 4, 0, 0x7f7f7f7f, 0, 0x7f7f7f7f);
                }
            }
        }
    }

    // ---- in-register scan reduction (C/D: col = lane&15, row = q*4 + reg) ----
    const float NEG = -1e30f;
    #pragma unroll
    for (int j = 0; j < 4; j++) {
        Seg S[4];
        #pragma unroll
        for (int i = 0; i < 4; i++) {
            float run = NEG, Cm = NEG, ACm = NEG;
            #pragma unroll
            for (int r = 0; r < 4; r++) {
                float c = acc1[i][j][r];
                ACm = fmaxf(ACm, run + c);
                Cm  = fmaxf(Cm, c);
                run = fmaxf(run, acc0[i][j][r]);
            }
            S[i].A = run; S[i].C = Cm; S[i].AC = ACm;
        }
        #pragma unroll
        for (int i = 0; i < 4; i++) S[i] = segCombine(S[i], segShflDown(S[i], 16));
        #pragma unroll
        for (int i = 0; i < 4; i++) S[i] = segCombine(S[i], segShflDown(S[i], 32));
        Seg W = S[0];
        #pragma unroll
        for (int i = 1; i < 4; i++) W = segCombine(W, S[i]);
        if (lane < 16) {
            int col = j * 16 + lane;
            sumBuf[col][wave][0] = W.A;   // wave index == l-order of 64-row group
            sumBuf[col][wave][1] = W.C;
            sumBuf[col][wave][2] = W.AC;
        }
    }
    __syncthreads();
    if (t < 64) {
        Seg w;
        w.A = sumBuf[t][0][0]; w.C = sumBuf[t][0][1]; w.AC = sumBuf[t][0][2];
        #pragma unroll
        for (int g = 1; g < 4; g++) {
            Seg y;
            y.A = sumBuf[t][g][0]; y.C = sumBuf[t][g][1]; y.AC = sumBuf[t][g][2];
            w = segCombine(w, y);
        }
        // un-scale: a,c carried x256 (X x2, W x128); max-plus commutes with it
        float h2 = fmaxf(0.f, fmaxf(w.C, w.AC)) * (1.0f / 256.0f);
        out[blockIdx.x * 1024 + n0 + t] = tanhf(h2 + bias[n0 + t]);
    }
}

extern "C" void kernel_launch(void* const* d_in, const int* in_sizes, int n_in,
                              void* d_out, int out_size, void* d_ws, size_t ws_size,
                              hipStream_t stream) {
    const float* X    = (const float*)d_in[0];  // [64,256,1024]
    const float* W0   = (const float*)d_in[1];  // [1024,1024]
    const float* W1   = (const float*)d_in[2];  // [1024,1024]
    const float* bias = (const float*)d_in[3];  // [1024]
    float* out = (float*)d_out;                 // [64,1024]

    char* ws = (char*)d_ws;
    unsigned char* Xf4 = (unsigned char*)(ws);              // 8 MB
    unsigned char* W0t = (unsigned char*)(ws + 8388608);    // 512 KB
    unsigned char* W1t = (unsigned char*)(ws + 8912896);    // 512 KB

    prep<<<dim3(6144), dim3(256), 0, stream>>>(X, W0, W1, Xf4, W0t, W1t);
    gemm_scan<<<dim3(64, 16), dim3(256), 0, stream>>>(Xf4, W0t, W1t, bias, out);
}